// Round 4
// baseline (1815.782 us; speedup 1.0000x reference)
//
#include <hip/hip_runtime.h>

#define NA 50000
#define NP 1600000
#define RA 16                    // atoms per range
#define NR (NA / RA)             // 3125 ranges
#define PAIR_BLOCKS 512          // 2 resident blocks/CU * 256 CUs
#define NB_SCAN 98               // ceil(NA/512)

// ws layout (bytes)
#define WS_X      0               // x: NA*128 f32 = 25,600,000
#define WS_W1T    25600000        // 128*40 bf16  = 10,240
#define WS_W2T    25610240        // 128*136 bf16 = 34,816
#define WS_WINT   25645056
#define WS_WO1T   25679872
#define WS_WO2T   25714688        // ends 25,749,504
#define WS_CNT    25749504        // 50000 i32 = 200,000
#define WS_START  25949504        // 50001 i32 = 200,004 (pad to 200,008)
#define WS_CURSOR 26149512        // 50000 i32 = 200,000
#define WS_BSUM   26349512        // 98 i32 (pad)
#define WS_BOFF   26350016        // 98 i32 (pad)
#define WS_PERM   26350400        // 1.6M i32 = 6,400,000 -> ends 32,750,400

typedef __attribute__((ext_vector_type(4))) float f32x4;
typedef __attribute__((ext_vector_type(8))) short short8;

#define MFMA(a, b, c) __builtin_amdgcn_mfma_f32_16x16x32_bf16((a), (b), (c), 0, 0, 0)

__device__ __forceinline__ unsigned short f2bf(float f) {
    unsigned int u = __float_as_uint(f);
    u += 0x7FFFu + ((u >> 16) & 1u);     // round-to-nearest-even
    return (unsigned short)(u >> 16);
}
__device__ __forceinline__ float bf2f(unsigned short h) {
    return __uint_as_float(((unsigned int)h) << 16);
}
// shifted softplus, numerically stable
__device__ __forceinline__ float ssp_f(float z) {
    float az = fabsf(z);
    float e  = __expf(-az);
    float l  = __logf(1.0f + e);
    return fmaxf(z, 0.0f) + l - 0.69314718056f;
}

// A stored [m][k] (LDA halfwords), B stored transposed [n][k] (LDB halfwords).
// A-frag: row=m0+(lane&15), k=ks*32+(lane>>4)*8+i ; C/D: col=lane&15, row=(lane>>4)*4+i
template <int LDA, int LDB, int KS, bool SPLIT>
__device__ __forceinline__ void gemm_t(const unsigned short* A, const unsigned short* Al,
                                       const unsigned short* B, int m0, int nc0,
                                       int lr, int lg, f32x4 (&acc)[2][4]) {
#pragma unroll
    for (int ks = 0; ks < KS; ++ks) {
        const int ko = ks * 32 + lg * 8;
        short8 a0 = *(const short8*)(A + (m0 + lr) * LDA + ko);
        short8 a1 = *(const short8*)(A + (m0 + 16 + lr) * LDA + ko);
        short8 a0l, a1l;
        if constexpr (SPLIT) {
            a0l = *(const short8*)(Al + (m0 + lr) * LDA + ko);
            a1l = *(const short8*)(Al + (m0 + 16 + lr) * LDA + ko);
        }
#pragma unroll
        for (int nt = 0; nt < 4; ++nt) {
            short8 b = *(const short8*)(B + (nc0 + nt * 16 + lr) * LDB + ko);
            acc[0][nt] = MFMA(a0, b, acc[0][nt]);
            acc[1][nt] = MFMA(a1, b, acc[1][nt]);
            if constexpr (SPLIT) {
                acc[0][nt] = MFMA(a0l, b, acc[0][nt]);
                acc[1][nt] = MFMA(a1l, b, acc[1][nt]);
            }
        }
    }
}

// =================== sort-by-idx_i infrastructure ===================
__global__ void hist_kernel(const int* __restrict__ idxI, int* __restrict__ cnt) {
    int p = blockIdx.x * 512 + threadIdx.x;
    if (p < NP) atomicAdd(&cnt[idxI[p]], 1);
}

__global__ void scanA_kernel(const int* __restrict__ cnt, int* __restrict__ bsum) {
    __shared__ int s[512];
    int tid = threadIdx.x;
    int i = blockIdx.x * 512 + tid;
    s[tid] = (i < NA) ? cnt[i] : 0;
    __syncthreads();
#pragma unroll
    for (int off = 256; off > 0; off >>= 1) {
        if (tid < off) s[tid] += s[tid + off];
        __syncthreads();
    }
    if (tid == 0) bsum[blockIdx.x] = s[0];
}

__global__ void scanB_kernel(const int* __restrict__ bsum, int* __restrict__ boff,
                             int* __restrict__ start) {
    __shared__ int s[128];
    int tid = threadIdx.x;
    int v = (tid < NB_SCAN) ? bsum[tid] : 0;
    s[tid] = v;
    __syncthreads();
#pragma unroll
    for (int off = 1; off < 128; off <<= 1) {
        int t = (tid >= off) ? s[tid - off] : 0;
        __syncthreads();
        s[tid] += t;
        __syncthreads();
    }
    if (tid < NB_SCAN) boff[tid] = s[tid] - v;   // exclusive
    if (tid == 0) start[NA] = s[127];            // total (= NP)
}

__global__ void scanC_kernel(const int* __restrict__ cnt, const int* __restrict__ boff,
                             int* __restrict__ start, int* __restrict__ cursor) {
    __shared__ int s[512];
    int tid = threadIdx.x;
    int i = blockIdx.x * 512 + tid;
    int v = (i < NA) ? cnt[i] : 0;
    s[tid] = v;
    __syncthreads();
#pragma unroll
    for (int off = 1; off < 512; off <<= 1) {
        int t = (tid >= off) ? s[tid - off] : 0;
        __syncthreads();
        s[tid] += t;
        __syncthreads();
    }
    if (i < NA) {
        int excl = s[tid] - v + boff[blockIdx.x];
        start[i] = excl;
        cursor[i] = excl;
    }
}

__global__ void scatter_kernel(const int* __restrict__ idxI, int* __restrict__ cursor,
                               int* __restrict__ perm) {
    int p = blockIdx.x * 512 + threadIdx.x;
    if (p < NP) {
        int pos = atomicAdd(&cursor[idxI[p]], 1);
        // agent-scope atomic store: neighboring entries of the same 64B line are
        // written by blocks on different XCDs; plain stores could clobber via
        // incoherent dirty L2 lines.
        __hip_atomic_store(&perm[pos], p, __ATOMIC_RELAXED, __HIP_MEMORY_SCOPE_AGENT);
    }
}

// =================== prep: weights -> bf16 [n][k] padded, transposed ===================
__global__ void prep_kernel(const float* __restrict__ Wf1, const float* __restrict__ Wf2,
                            const float* __restrict__ Win, const float* __restrict__ Wo1,
                            const float* __restrict__ Wo2, unsigned short* __restrict__ w1t,
                            unsigned short* __restrict__ w2t, unsigned short* __restrict__ wint,
                            unsigned short* __restrict__ wo1t, unsigned short* __restrict__ wo2t) {
    const int n = blockIdx.x;    // 0..127 output col
    const int k = threadIdx.x;
    const int m = blockIdx.y;
    if (m == 0) {
        if (k < 40) w1t[n * 40 + k] = (k < 20) ? f2bf(Wf1[k * 128 + n]) : (unsigned short)0;
    } else {
        const float* src = (m == 1) ? Wf2 : (m == 2) ? Win : (m == 3) ? Wo1 : Wo2;
        unsigned short* dst = (m == 1) ? w2t : (m == 2) ? wint : (m == 3) ? wo1t : wo2t;
        if (k < 136) dst[n * 136 + k] = (k < 128) ? f2bf(src[k * 128 + n]) : (unsigned short)0;
    }
}

// =================== xproj: x = emb @ W_in (split-A bf16 MFMA) ===================
__global__ __launch_bounds__(512, 2) void xproj_kernel(const float* __restrict__ emb,
                                                       const unsigned short* __restrict__ wint,
                                                       float* __restrict__ x) {
    __shared__ __align__(16) unsigned short sAh[128 * 136];
    __shared__ __align__(16) unsigned short sAl[128 * 136];
    __shared__ __align__(16) unsigned short sW[128 * 136];
    const int tid = threadIdx.x;
    const int r0 = blockIdx.x * 128;
#pragma unroll
    for (int it = 0; it < 32; ++it) {
        int idx = it * 512 + tid;
        int row = idx >> 7, col = idx & 127;
        int r = r0 + row;
        float v = (r < NA) ? emb[(size_t)r * 128 + col] : 0.0f;
        unsigned short hi = f2bf(v);
        unsigned short lo = f2bf(v - bf2f(hi));
        sAh[row * 136 + col] = hi;
        sAl[row * 136 + col] = lo;
    }
    {
        const unsigned int* s = (const unsigned int*)wint;
        unsigned int* d = (unsigned int*)sW;
        for (int i = tid; i < 128 * 136 / 2; i += 512) d[i] = s[i];
    }
    __syncthreads();
    const int lane = tid & 63, wave = tid >> 6;
    const int lr = lane & 15, lg = lane >> 4;
    const int m0 = (wave & 3) * 32, nc0 = (wave >> 2) * 64;
    f32x4 acc[2][4] = {};
    gemm_t<136, 136, 4, true>(sAh, sAl, sW, m0, nc0, lr, lg, acc);
#pragma unroll
    for (int mt = 0; mt < 2; ++mt)
#pragma unroll
        for (int i = 0; i < 4; ++i) {
            int rl = m0 + mt * 16 + lg * 4 + i;
            int r = r0 + rl;
            if (r < NA) {
#pragma unroll
                for (int nt = 0; nt < 4; ++nt) {
                    int col = nc0 + nt * 16 + lr;
                    x[(size_t)r * 128 + col] = acc[mt][nt][i];
                }
            }
        }
}

// =================== pair kernel v3: sorted ranges, LDS accumulation ===================
// 256 threads (4 waves), 64-pair tiles, 16-atom ranges, no global atomics.
// LDS = 77.6 KB -> 2 independent blocks/CU for cross-block latency hiding.
__global__ __launch_bounds__(256, 2) void pair_kernel(
        const float* __restrict__ fij, const float* __restrict__ fcut,
        const int* __restrict__ idxI, const int* __restrict__ idxJ,
        const int* __restrict__ start, const int* __restrict__ perm,
        const float* __restrict__ x, const unsigned short* __restrict__ w1t,
        const unsigned short* __restrict__ w2t, const float* __restrict__ bf1,
        const float* __restrict__ bf2, float* __restrict__ out) {
    __shared__ __align__(16) unsigned short sW1[128 * 40];    // 10,240
    __shared__ __align__(16) unsigned short sW2[128 * 136];   // 34,816
    __shared__ __align__(16) unsigned short sF[64 * 40];      //  5,120
    __shared__ __align__(16) unsigned short sH[64 * 136];     // 17,408
    __shared__ float sAcc[RA * 128];                          //  8,192
    __shared__ float sB1[128], sB2[128];
    __shared__ float sCut[64];
    __shared__ int sJJ[64], sLa[64];

    const int tid = threadIdx.x;
    {   // stage weights once per block; zero sF K-pads (k in [20,32) stays 0 forever)
        const unsigned int* s1 = (const unsigned int*)w1t;
        unsigned int* d1 = (unsigned int*)sW1;
        for (int i = tid; i < 128 * 40 / 2; i += 256) d1[i] = s1[i];
        const unsigned int* s2 = (const unsigned int*)w2t;
        unsigned int* d2 = (unsigned int*)sW2;
        for (int i = tid; i < 128 * 136 / 2; i += 256) d2[i] = s2[i];
        if (tid < 128) { sB1[tid] = bf1[tid]; sB2[tid] = bf2[tid]; }
        unsigned int* z = (unsigned int*)sF;
        for (int i = tid; i < 64 * 40 / 2; i += 256) z[i] = 0;
    }
    const int lane = tid & 63, wave = tid >> 6;
    const int lr = lane & 15, lg = lane >> 4;
    const int m0 = (wave & 1) * 32, nc0 = (wave >> 1) * 64;
    const int srow = tid >> 2, sq = tid & 3;   // fij staging: 4 threads per pair row

    for (int r = blockIdx.x; r < NR; r += gridDim.x) {
        const int a0 = r * RA;
        const int s = start[a0], e = start[a0 + RA];
        for (int i = tid; i < RA * 128; i += 256) sAcc[i] = 0.0f;
        __syncthreads();

        const int ntile = (e - s + 63) >> 6;
        for (int tl = 0; tl < ntile; ++tl) {
            const int base = s + tl * 64;
            {   // stage f_ij tile (stale rows for invalid slots are nullified by cut=0)
                int slot = base + srow;
                if (slot < e) {
                    int pid = perm[slot];
                    const float* fr = fij + (size_t)pid * 20 + sq * 5;
#pragma unroll
                    for (int u = 0; u < 5; ++u) sF[srow * 40 + sq * 5 + u] = f2bf(fr[u]);
                }
                if (tid < 64) {
                    int slot2 = base + tid;
                    if (slot2 < e) {
                        int pid2 = perm[slot2];
                        sJJ[tid] = idxJ[pid2];
                        sCut[tid] = fcut[pid2];
                        sLa[tid] = idxI[pid2] - a0;
                    } else { sJJ[tid] = 0; sCut[tid] = 0.0f; sLa[tid] = 0; }
                }
            }
            __syncthreads();   // sF + sideband ready

            // x-gather prefetch (T14): issue now, consume after GEMM2 (~1000cy later)
            float xp[2][4][4];
#pragma unroll
            for (int mt = 0; mt < 2; ++mt)
#pragma unroll
                for (int i = 0; i < 4; ++i) {
                    int rl = m0 + mt * 16 + lg * 4 + i;
                    const float* xr = x + (size_t)sJJ[rl] * 128;
#pragma unroll
                    for (int nt = 0; nt < 4; ++nt)
                        xp[mt][i][nt] = xr[nc0 + nt * 16 + lr];
                }

            // GEMM1: h = f_ij @ W_f1 (K=32 incl. zero pad)
            f32x4 acc1[2][4] = {};
            gemm_t<40, 40, 1, false>(sF, nullptr, sW1, m0, nc0, lr, lg, acc1);

            // ssp(h + b1) -> sH (bf16)
#pragma unroll
            for (int mt = 0; mt < 2; ++mt)
#pragma unroll
                for (int nt = 0; nt < 4; ++nt) {
                    int col = nc0 + nt * 16 + lr;
                    float b1 = sB1[col];
#pragma unroll
                    for (int i = 0; i < 4; ++i) {
                        int rl = m0 + mt * 16 + lg * 4 + i;
                        sH[rl * 136 + col] = f2bf(ssp_f(acc1[mt][nt][i] + b1));
                    }
                }
            __syncthreads();   // sH ready

            // GEMM2: W_ij = h @ W_f2 (K=128)
            f32x4 acc2[2][4] = {};
            gemm_t<136, 136, 4, false>(sH, nullptr, sW2, m0, nc0, lr, lg, acc2);

            // epilogue: (+b2)*cut*x[j]  ->  LDS accumulation (ds_add_f32)
#pragma unroll
            for (int mt = 0; mt < 2; ++mt)
#pragma unroll
                for (int i = 0; i < 4; ++i) {
                    int rl = m0 + mt * 16 + lg * 4 + i;
                    float cc = sCut[rl];
                    float* arow = &sAcc[sLa[rl] * 128];
#pragma unroll
                    for (int nt = 0; nt < 4; ++nt) {
                        int col = nc0 + nt * 16 + lr;
                        float v = (acc2[mt][nt][i] + sB2[col]) * cc * xp[mt][i][nt];
                        atomicAdd(&arow[col], v);
                    }
                }
            __syncthreads();   // epilogue done before next tile overwrites sF/sideband
        }

        // write this range's 16 atom rows (disjoint across blocks -> plain stores),
        // re-zeroing is done by the same thread that read each element (no race).
        for (int i = tid; i < RA * 128; i += 256) {
            int la = i >> 7, c = i & 127;
            out[((size_t)(a0 + la)) * 128 + c] = sAcc[i];
        }
    }
}

// =================== output MLP, in-place on d_out (split-A bf16 MFMA) ===================
__global__ __launch_bounds__(512, 2) void mlp_kernel(const unsigned short* __restrict__ wo1t,
                                                     const unsigned short* __restrict__ wo2t,
                                                     const float* __restrict__ bo1,
                                                     const float* __restrict__ bo2,
                                                     float* __restrict__ out) {
    __shared__ __align__(16) unsigned short sAh[128 * 136];
    __shared__ __align__(16) unsigned short sAl[128 * 136];
    __shared__ __align__(16) unsigned short sW[128 * 136];
    __shared__ float sb1[128], sb2[128];
    const int tid = threadIdx.x;
    const int r0 = blockIdx.x * 128;
#pragma unroll
    for (int it = 0; it < 32; ++it) {
        int idx = it * 512 + tid;
        int row = idx >> 7, col = idx & 127;
        int r = r0 + row;
        float v = (r < NA) ? out[(size_t)r * 128 + col] : 0.0f;
        unsigned short hi = f2bf(v);
        unsigned short lo = f2bf(v - bf2f(hi));
        sAh[row * 136 + col] = hi;
        sAl[row * 136 + col] = lo;
    }
    {
        const unsigned int* s = (const unsigned int*)wo1t;
        unsigned int* d = (unsigned int*)sW;
        for (int i = tid; i < 128 * 136 / 2; i += 512) d[i] = s[i];
    }
    if (tid < 128) { sb1[tid] = bo1[tid]; sb2[tid] = bo2[tid]; }
    __syncthreads();
    const int lane = tid & 63, wave = tid >> 6;
    const int lr = lane & 15, lg = lane >> 4;
    const int m0 = (wave & 3) * 32, nc0 = (wave >> 2) * 64;

    f32x4 acc[2][4] = {};
    gemm_t<136, 136, 4, true>(sAh, sAl, sW, m0, nc0, lr, lg, acc);
    __syncthreads();

    // h = ssp(acc + b1) -> sAh; restage sW <- Wo2T
#pragma unroll
    for (int mt = 0; mt < 2; ++mt)
#pragma unroll
        for (int nt = 0; nt < 4; ++nt) {
            int col = nc0 + nt * 16 + lr;
            float b1 = sb1[col];
#pragma unroll
            for (int i = 0; i < 4; ++i) {
                int rl = m0 + mt * 16 + lg * 4 + i;
                sAh[rl * 136 + col] = f2bf(ssp_f(acc[mt][nt][i] + b1));
            }
        }
    {
        const unsigned int* s = (const unsigned int*)wo2t;
        unsigned int* d = (unsigned int*)sW;
        for (int i = tid; i < 128 * 136 / 2; i += 512) d[i] = s[i];
    }
    __syncthreads();

    f32x4 acc2[2][4] = {};
    gemm_t<136, 136, 4, false>(sAh, nullptr, sW, m0, nc0, lr, lg, acc2);
#pragma unroll
    for (int mt = 0; mt < 2; ++mt)
#pragma unroll
        for (int i = 0; i < 4; ++i) {
            int rl = m0 + mt * 16 + lg * 4 + i;
            int r = r0 + rl;
            if (r < NA) {
#pragma unroll
                for (int nt = 0; nt < 4; ++nt) {
                    int col = nc0 + nt * 16 + lr;
                    out[(size_t)r * 128 + col] = acc2[mt][nt][i] + sb2[col];
                }
            }
        }
}

extern "C" void kernel_launch(void* const* d_in, const int* in_sizes, int n_in,
                              void* d_out, int out_size, void* d_ws, size_t ws_size,
                              hipStream_t stream) {
    const float* emb  = (const float*)d_in[0];
    const int*   pidx = (const int*)d_in[1];
    const float* fij  = (const float*)d_in[2];
    const float* fcut = (const float*)d_in[3];
    const float* Win  = (const float*)d_in[4];
    const float* Wf1  = (const float*)d_in[5];
    const float* bf1  = (const float*)d_in[6];
    const float* Wf2  = (const float*)d_in[7];
    const float* bf2  = (const float*)d_in[8];
    const float* Wo1  = (const float*)d_in[9];
    const float* bo1  = (const float*)d_in[10];
    const float* Wo2  = (const float*)d_in[11];
    const float* bo2  = (const float*)d_in[12];
    float* out = (float*)d_out;
    char* ws = (char*)d_ws;

    const int* idxI = pidx;
    const int* idxJ = pidx + NP;

    float* x = (float*)(ws + WS_X);
    unsigned short* w1t  = (unsigned short*)(ws + WS_W1T);
    unsigned short* w2t  = (unsigned short*)(ws + WS_W2T);
    unsigned short* wint = (unsigned short*)(ws + WS_WINT);
    unsigned short* wo1t = (unsigned short*)(ws + WS_WO1T);
    unsigned short* wo2t = (unsigned short*)(ws + WS_WO2T);
    int* cnt    = (int*)(ws + WS_CNT);
    int* start  = (int*)(ws + WS_START);
    int* cursor = (int*)(ws + WS_CURSOR);
    int* bsum   = (int*)(ws + WS_BSUM);
    int* boff   = (int*)(ws + WS_BOFF);
    int* perm   = (int*)(ws + WS_PERM);

    // counting sort of pairs by idx_i
    hipMemsetAsync(cnt, 0, NA * sizeof(int), stream);
    hist_kernel<<<NP / 512, 512, 0, stream>>>(idxI, cnt);
    scanA_kernel<<<NB_SCAN, 512, 0, stream>>>(cnt, bsum);
    scanB_kernel<<<1, 128, 0, stream>>>(bsum, boff, start);
    scanC_kernel<<<NB_SCAN, 512, 0, stream>>>(cnt, boff, start, cursor);
    scatter_kernel<<<NP / 512, 512, 0, stream>>>(idxI, cursor, perm);

    prep_kernel<<<dim3(128, 5), 256, 0, stream>>>(Wf1, Wf2, Win, Wo1, Wo2,
                                                  w1t, w2t, wint, wo1t, wo2t);
    xproj_kernel<<<(NA + 127) / 128, 512, 0, stream>>>(emb, wint, x);
    pair_kernel<<<PAIR_BLOCKS, 256, 0, stream>>>(fij, fcut, idxI, idxJ, start, perm, x,
                                                 w1t, w2t, bf1, bf2, out);
    mlp_kernel<<<(NA + 127) / 128, 512, 0, stream>>>(wo1t, wo2t, bo1, bo2, out);
}